// Round 1
// baseline (424.695 us; speedup 1.0000x reference)
//
#include <hip/hip_runtime.h>
#include <stdint.h>

#define NNODES 100000
#define NEDGES 400000
#define DD 128

typedef __attribute__((ext_vector_type(4))) float f32x4;
typedef __attribute__((ext_vector_type(8))) short bf16x8;

__device__ __forceinline__ short f2b(float x){
  union { float f; uint32_t u; } v; v.f = x;
  uint32_t r = v.u + 0x7FFFu + ((v.u >> 16) & 1u);
  return (short)(r >> 16);
}

__device__ __forceinline__ bf16x8 pack_bf8(f32x4 a, f32x4 b){
  bf16x8 r;
  r[0]=f2b(a[0]); r[1]=f2b(a[1]); r[2]=f2b(a[2]); r[3]=f2b(a[3]);
  r[4]=f2b(b[0]); r[5]=f2b(b[1]); r[6]=f2b(b[2]); r[7]=f2b(b[3]);
  return r;
}

// Pack f32 weight [K][128] into bf16 tiles: dst[kt][g][n][j] = bf16(W[kt*32+g*8+j][n])
__global__ void pack_w_kernel(const float* __restrict__ W, short* __restrict__ dst, int total){
  int o = blockIdx.x*256 + threadIdx.x;
  if (o >= total) return;
  int kt = o >> 12, rem = o & 4095;
  int g = rem >> 10, n = (rem >> 3) & 127, j = rem & 7;
  int k = kt*32 + g*8 + j;
  dst[o] = f2b(W[k*DD + n]);
}

// MODE 0: edge MLP (K1=384, gather snd/rcv/edge, epilogue: out=LN+edge, atomicAdd LN->agg[rcv])
// MODE 1: node MLP (K1=256, inputs nodes|agg,   epilogue: out=LN+node)
template<int MODE>
__global__ __launch_bounds__(256, 2) void gnb_mlp(
    const float* __restrict__ nodef, const float* __restrict__ edgef,
    const int* __restrict__ snd, const int* __restrict__ rcv,
    const short* __restrict__ Wp1, const short* __restrict__ Wp2, const short* __restrict__ Wp3,
    const float* __restrict__ b1p, const float* __restrict__ b2p, const float* __restrict__ b3p,
    const float* __restrict__ gmp, const float* __restrict__ btp,
    float* __restrict__ agg, float* __restrict__ outp, int nrows)
{
  constexpr int KT1 = (MODE==0) ? 12 : 8;   // k-tiles of 32 in layer 1
  __shared__ __align__(16) short Ws[4096];  // [4 g][128 n][8 j] bf16 = 8KB, one W k-tile
  __shared__ __align__(16) short Hs[8192];  // [64][128] bf16 row-major, XOR-swizzled, 16KB

  const int tid  = threadIdx.x;
  const int lane = tid & 63;
  const int wid  = tid >> 6;        // wave 0..3 owns rows [wid*16, wid*16+16)
  const int l16  = lane & 15;
  const int hi   = lane >> 4;
  const int row0 = blockIdx.x * 64;
  const int arow_l = wid*16 + l16;                      // local row for A-fragments
  const int arow_g = row0 + arow_l;
  const int arow_c = (arow_g < nrows) ? arow_g : (nrows-1);

  int sidx = 0, ridx = 0;
  if (MODE==0){ sidx = snd[arow_c]; ridx = rcv[arow_c]; }

  f32x4 acc[8];
  #pragma unroll
  for (int t=0;t<8;t++) acc[t] = (f32x4)(0.0f);

  // ---------------- layer 1: A direct from global (gather), W streamed via LDS ----------------
  #pragma unroll
  for (int kt=0; kt<KT1; kt++){
    const int4* ws_src = (const int4*)(Wp1 + kt*4096);
    int4 w0 = ws_src[tid]; int4 w1 = ws_src[tid+256];
    __syncthreads();
    ((int4*)Ws)[tid] = w0; ((int4*)Ws)[tid+256] = w1;
    __syncthreads();

    const float* s;
    if (MODE==0){
      s = (kt<4) ? (nodef + (size_t)sidx*DD)
        : (kt<8) ? (nodef + (size_t)ridx*DD)
                 : (edgef + (size_t)arow_c*DD);
    } else {
      s = (kt<4) ? (nodef + (size_t)arow_c*DD) : (agg + (size_t)arow_c*DD);
    }
    const int ko = (kt&3)*32 + hi*8;
    f32x4 x0 = *(const f32x4*)(s+ko);
    f32x4 x1 = *(const f32x4*)(s+ko+4);
    bf16x8 af = pack_bf8(x0,x1);
    #pragma unroll
    for (int t=0;t<8;t++){
      bf16x8 bw = *(const bf16x8*)&Ws[hi*1024 + (t*16+l16)*8];
      acc[t] = __builtin_amdgcn_mfma_f32_16x16x32_bf16(af, bw, acc[t], 0,0,0);
    }
  }
  // epilogue 1: bias + relu -> Hs (bf16, swizzled); per-wave rows only, no barrier needed
  #pragma unroll
  for (int t=0;t<8;t++){
    const float bb = b1p[t*16+l16];
    const int col2 = (t*16+l16)*2;
    #pragma unroll
    for (int r=0;r<4;r++){
      float v = fmaxf(acc[t][r] + bb, 0.0f);
      int row = wid*16 + hi*4 + r;
      *(short*)((char*)Hs + row*256 + (col2 ^ ((row&7)<<4))) = f2b(v);
      acc[t][r] = 0.0f;
    }
  }

  // ---------------- layers 2 and 3: A from Hs ----------------
  #pragma unroll
  for (int L=0; L<2; L++){
    const short* Wp = (L==0) ? Wp2 : Wp3;
    #pragma unroll
    for (int kt=0; kt<4; kt++){
      const int4* ws_src = (const int4*)(Wp + kt*4096);
      int4 w0 = ws_src[tid]; int4 w1 = ws_src[tid+256];
      __syncthreads();
      ((int4*)Ws)[tid] = w0; ((int4*)Ws)[tid+256] = w1;
      __syncthreads();
      bf16x8 af = *(const bf16x8*)((char*)Hs + arow_l*256 + ((kt*64 + hi*16) ^ ((arow_l&7)<<4)));
      #pragma unroll
      for (int t=0;t<8;t++){
        bf16x8 bw = *(const bf16x8*)&Ws[hi*1024 + (t*16+l16)*8];
        acc[t] = __builtin_amdgcn_mfma_f32_16x16x32_bf16(af, bw, acc[t], 0,0,0);
      }
    }
    if (L==0){
      #pragma unroll
      for (int t=0;t<8;t++){
        const float bb = b2p[t*16+l16];
        const int col2 = (t*16+l16)*2;
        #pragma unroll
        for (int r=0;r<4;r++){
          float v = fmaxf(acc[t][r] + bb, 0.0f);
          int row = wid*16 + hi*4 + r;
          *(short*)((char*)Hs + row*256 + (col2 ^ ((row&7)<<4))) = f2b(v);
          acc[t][r] = 0.0f;
        }
      }
    }
  }

  // ---------------- LayerNorm (in-register) + epilogue ----------------
  float ps[4] = {0,0,0,0}, pq[4] = {0,0,0,0};
  #pragma unroll
  for (int t=0;t<8;t++){
    const float bb = b3p[t*16+l16];
    #pragma unroll
    for (int r=0;r<4;r++){
      float v = acc[t][r] + bb;
      acc[t][r] = v;
      ps[r] += v; pq[r] += v*v;
    }
  }
  // butterfly over the 16 lanes sharing hi (xor masks < 16 stay in group)
  #pragma unroll
  for (int m=1;m<16;m<<=1){
    #pragma unroll
    for (int r=0;r<4;r++){
      ps[r] += __shfl_xor(ps[r], m);
      pq[r] += __shfl_xor(pq[r], m);
    }
  }
  float mu[4], rs[4];
  #pragma unroll
  for (int r=0;r<4;r++){
    mu[r] = ps[r] * (1.0f/128.0f);
    float var = pq[r] * (1.0f/128.0f) - mu[r]*mu[r];
    rs[r] = rsqrtf(var + 1e-5f);
  }

  int erow[4]; int rdst[4] = {0,0,0,0};
  #pragma unroll
  for (int r=0;r<4;r++){
    erow[r] = row0 + wid*16 + hi*4 + r;
    if (MODE==0) rdst[r] = rcv[erow[r]];
  }

  #pragma unroll
  for (int t=0;t<8;t++){
    const int col = t*16+l16;
    const float g = gmp[col], be = btp[col];
    #pragma unroll
    for (int r=0;r<4;r++){
      float y = (acc[t][r]-mu[r])*rs[r]*g + be;
      if (MODE==0){
        size_t o = (size_t)erow[r]*DD + col;
        outp[o] = y + edgef[o];
        atomicAdd(agg + (size_t)rdst[r]*DD + col, y);
      } else {
        if (erow[r] < nrows){
          size_t o = (size_t)erow[r]*DD + col;
          outp[o] = y + nodef[o];
        }
      }
    }
  }
}

extern "C" void kernel_launch(void* const* d_in, const int* in_sizes, int n_in,
                              void* d_out, int out_size, void* d_ws, size_t ws_size,
                              hipStream_t stream)
{
  (void)in_sizes; (void)n_in; (void)out_size; (void)ws_size;
  const float* nodef = (const float*)d_in[0];
  const float* edgef = (const float*)d_in[1];
  const int*   snd   = (const int*)d_in[2];
  const int*   rcv   = (const int*)d_in[3];
  const float* eW1 = (const float*)d_in[4];
  const float* eb1 = (const float*)d_in[5];
  const float* eW2 = (const float*)d_in[6];
  const float* eb2 = (const float*)d_in[7];
  const float* eW3 = (const float*)d_in[8];
  const float* eb3 = (const float*)d_in[9];
  const float* egm = (const float*)d_in[10];
  const float* ebt = (const float*)d_in[11];
  const float* nW1 = (const float*)d_in[12];
  const float* nb1 = (const float*)d_in[13];
  const float* nW2 = (const float*)d_in[14];
  const float* nb2 = (const float*)d_in[15];
  const float* nW3 = (const float*)d_in[16];
  const float* nb3 = (const float*)d_in[17];
  const float* ngm = (const float*)d_in[18];
  const float* nbt = (const float*)d_in[19];

  float* agg = (float*)d_ws;                                        // [N,128] f32 = 51.2MB
  short* wp  = (short*)((char*)d_ws + (size_t)NNODES*DD*sizeof(float));
  short* we1 = wp;             // 384*128 = 49152
  short* we2 = wp + 49152;     // 16384
  short* we3 = wp + 65536;     // 16384
  short* wn1 = wp + 81920;     // 32768
  short* wn2 = wp + 114688;    // 16384
  short* wn3 = wp + 131072;    // 16384

  hipMemsetAsync(agg, 0, (size_t)NNODES*DD*sizeof(float), stream);
  pack_w_kernel<<<192,256,0,stream>>>(eW1, we1, 49152);
  pack_w_kernel<<<64, 256,0,stream>>>(eW2, we2, 16384);
  pack_w_kernel<<<64, 256,0,stream>>>(eW3, we3, 16384);
  pack_w_kernel<<<128,256,0,stream>>>(nW1, wn1, 32768);
  pack_w_kernel<<<64, 256,0,stream>>>(nW2, wn2, 16384);
  pack_w_kernel<<<64, 256,0,stream>>>(nW3, wn3, 16384);

  float* out_nodes = (float*)d_out;
  float* out_edges = out_nodes + (size_t)NNODES*DD;

  gnb_mlp<0><<<NEDGES/64, 256, 0, stream>>>(nodef, edgef, snd, rcv,
      we1, we2, we3, eb1, eb2, eb3, egm, ebt, agg, out_edges, NEDGES);
  gnb_mlp<1><<<(NNODES+63)/64, 256, 0, stream>>>(nodef, edgef, snd, rcv,
      wn1, wn2, wn3, nb1, nb2, nb3, ngm, nbt, agg, out_nodes, NNODES);
}